// Round 1
// baseline (3998.262 us; speedup 1.0000x reference)
//
#include <hip/hip_runtime.h>

// ---------------------------------------------------------------------------
// MalwareGNN: 3-layer GCN (transform -> normalized aggregate) + mean pool + FC
// Strategy:
//   * detect int32 vs int64 indices on device (flag in ws)
//   * build dst-CSR once per call: deg histogram -> 3-kernel exclusive scan ->
//     atomic-cursor scatter (atomics only touch 400KB, L2-resident)
//   * per layer: GEMM with fused dinv scaling (hs = dinv * (x@W)), then
//     gather-aggregate: wave-per-node, lane = feature, coalesced 256B reads
//   * self-loops handled analytically: out = relu(dinv*(hs[i]+sum hs[src])+b)
//   * mean-pool via per-graph binary search on sorted batch, then tiny FC
// ---------------------------------------------------------------------------

__global__ void k_detect(const unsigned* __restrict__ ei, int* __restrict__ flag) {
  __shared__ int any;
  if (threadIdx.x == 0) any = 0;
  __syncthreads();
  unsigned v = 0;
  for (int i = threadIdx.x; i < 8192; i += blockDim.x) v |= ei[2 * i + 1];
  if (v) atomicOr(&any, 1);
  __syncthreads();
  if (threadIdx.x == 0) *flag = (any == 0) ? 1 : 0;  // 1 => int64 indices
}

__device__ __forceinline__ int load_idx(const void* p, long long i, bool wide) {
  return wide ? (int)((const long long*)p)[i] : ((const int*)p)[i];
}

__global__ void k_deg(const void* __restrict__ ei, int E, const int* __restrict__ flag,
                      int* __restrict__ deg) {
  bool wide = (*flag != 0);
  for (int e = blockIdx.x * blockDim.x + threadIdx.x; e < E; e += gridDim.x * blockDim.x) {
    int d = load_idx(ei, (long long)E + e, wide);
    atomicAdd(&deg[d], 1);
  }
}

__global__ void k_dinv(const int* __restrict__ deg, float* __restrict__ dinv, int N) {
  int i = blockIdx.x * blockDim.x + threadIdx.x;
  if (i < N) dinv[i] = rsqrtf((float)(deg[i] + 1));  // +1 self loop
}

// ---- exclusive scan of deg[N] -> rowptr[N+1], 2048 items/block -------------
__global__ void k_scan_a(const int* __restrict__ deg, int N, int* __restrict__ bsum) {
  __shared__ int sh[256];
  int base = blockIdx.x * 2048;
  int s = 0;
  for (int i = threadIdx.x; i < 2048; i += 256) {
    int idx = base + i;
    s += (idx < N) ? deg[idx] : 0;
  }
  sh[threadIdx.x] = s;
  __syncthreads();
  for (int off = 128; off > 0; off >>= 1) {
    if (threadIdx.x < off) sh[threadIdx.x] += sh[threadIdx.x + off];
    __syncthreads();
  }
  if (threadIdx.x == 0) bsum[blockIdx.x] = sh[0];
}

__global__ void k_scan_b(int* __restrict__ bsum, int nb) {
  if (threadIdx.x == 0) {
    int run = 0;
    for (int i = 0; i < nb; ++i) { int v = bsum[i]; bsum[i] = run; run += v; }
    bsum[nb] = run;
  }
}

__global__ void k_scan_c(const int* __restrict__ deg, int N, const int* __restrict__ bsum,
                         int* __restrict__ rowptr, int nb) {
  __shared__ int sh[256];
  int base = blockIdx.x * 2048;
  int v[8];
  int s = 0;
#pragma unroll
  for (int j = 0; j < 8; ++j) {
    int idx = base + threadIdx.x * 8 + j;
    v[j] = (idx < N) ? deg[idx] : 0;
    s += v[j];
  }
  sh[threadIdx.x] = s;
  __syncthreads();
  for (int off = 1; off < 256; off <<= 1) {
    int t = (threadIdx.x >= off) ? sh[threadIdx.x - off] : 0;
    __syncthreads();
    sh[threadIdx.x] += t;
    __syncthreads();
  }
  int excl = (threadIdx.x ? sh[threadIdx.x - 1] : 0) + bsum[blockIdx.x];
#pragma unroll
  for (int j = 0; j < 8; ++j) {
    int idx = base + threadIdx.x * 8 + j;
    if (idx < N) rowptr[idx] = excl;
    excl += v[j];
  }
  if (blockIdx.x == gridDim.x - 1 && threadIdx.x == 255) rowptr[N] = bsum[nb];
}

__global__ void k_scatter(const void* __restrict__ ei, int E, const int* __restrict__ flag,
                          const int* __restrict__ rowptr, int* __restrict__ cursor,
                          int* __restrict__ csr) {
  bool wide = (*flag != 0);
  for (int e = blockIdx.x * blockDim.x + threadIdx.x; e < E; e += gridDim.x * blockDim.x) {
    int s = load_idx(ei, e, wide);
    int d = load_idx(ei, (long long)E + e, wide);
    int pos = rowptr[d] + atomicAdd(&cursor[d], 1);
    csr[pos] = s;
  }
}

// ---- hs = dinv * (X @ W), wave computes 4 rows x 64 cols -------------------
template <int K>
__global__ void k_gemm_hs(const float* __restrict__ X, const float* __restrict__ W,
                          const float* __restrict__ dinv, float* __restrict__ HS, int N) {
  __shared__ float Wl[K * 64];
  for (int i = threadIdx.x; i < K * 64; i += blockDim.x) Wl[i] = W[i];
  __syncthreads();
  const int NX = K / 64;
  int lane = threadIdx.x & 63;
  int wid = threadIdx.x >> 6;
  int wavesPerBlock = blockDim.x >> 6;
  long long gwave = (long long)blockIdx.x * wavesPerBlock + wid;
  long long nwaves = (long long)wavesPerBlock * gridDim.x;
  for (long long r0 = gwave * 4; r0 < N; r0 += nwaves * 4) {
    int rcnt = (int)((N - r0) < 4 ? (N - r0) : 4);
    float xv[4][NX];
#pragma unroll
    for (int r = 0; r < 4; ++r) {
      long long row = r0 + (r < rcnt ? r : 0);
#pragma unroll
      for (int u = 0; u < NX; ++u) xv[r][u] = X[row * K + u * 64 + lane];
    }
    float acc[4] = {0.f, 0.f, 0.f, 0.f};
#pragma unroll
    for (int u = 0; u < NX; ++u) {
#pragma unroll
      for (int k = 0; k < 64; ++k) {
        float wv = Wl[(u * 64 + k) * 64 + lane];
#pragma unroll
        for (int r = 0; r < 4; ++r) acc[r] += __shfl(xv[r][u], k, 64) * wv;
      }
    }
    for (int r = 0; r < rcnt; ++r) {
      long long row = r0 + r;
      HS[row * 64 + lane] = dinv[row] * acc[r];
    }
  }
}

// ---- out[i] = relu(dinv[i]*(hs[i] + sum_{src in(i)} hs[src]) + b) ----------
__global__ void k_agg(const float* __restrict__ HS, const int* __restrict__ rowptr,
                      const int* __restrict__ csr, const float* __restrict__ dinv,
                      const float* __restrict__ bias, float* __restrict__ OUT, int N) {
  int lane = threadIdx.x & 63;
  int wid = threadIdx.x >> 6;
  int wavesPerBlock = blockDim.x >> 6;
  float b = bias[lane];
  for (int node = blockIdx.x * wavesPerBlock + wid; node < N;
       node += wavesPerBlock * gridDim.x) {
    int s0 = rowptr[node], s1 = rowptr[node + 1];
    float acc = HS[(long long)node * 64 + lane];  // self loop (dinv^2 after scale)
    for (int base = s0; base < s1; base += 64) {
      int m = s1 - base;
      if (m > 64) m = 64;
      int idx = (base + lane < s1) ? csr[base + lane] : 0;
      for (int j = 0; j < m; ++j) {
        int s = __shfl(idx, j, 64);
        acc += HS[(long long)s * 64 + lane];
      }
    }
    OUT[(long long)node * 64 + lane] = fmaxf(fmaf(dinv[node], acc, b), 0.f);
  }
}

// ---- mean pool per graph (batch is sorted) ---------------------------------
__global__ void k_pool(const float* __restrict__ H, const void* __restrict__ batch,
                       const int* __restrict__ flag, float* __restrict__ pooled, int N) {
  __shared__ int se[2];
  __shared__ float red[4][64];
  bool wide = (*flag != 0);
  int g = blockIdx.x;
  if (threadIdx.x < 2) {
    int target = g + threadIdx.x;
    int lo = 0, hi = N;
    while (lo < hi) {
      int mid = (lo + hi) >> 1;
      long long v = wide ? ((const long long*)batch)[mid] : (long long)((const int*)batch)[mid];
      if (v < target) lo = mid + 1; else hi = mid;
    }
    se[threadIdx.x] = lo;
  }
  __syncthreads();
  int s = se[0], e = se[1];
  int lane = threadIdx.x & 63, wid = threadIdx.x >> 6;
  float acc = 0.f;
  for (int r = s + wid; r < e; r += 4) acc += H[(long long)r * 64 + lane];
  red[wid][lane] = acc;
  __syncthreads();
  if (wid == 0) {
    float v = red[0][lane] + red[1][lane] + red[2][lane] + red[3][lane];
    float cnt = (float)(e - s);
    pooled[g * 64 + lane] = v / fmaxf(cnt, 1.f);
  }
}

__global__ void k_classify(const float* __restrict__ pooled, const float* __restrict__ Wc,
                           const float* __restrict__ bc, float* __restrict__ out, int total) {
  int t = blockIdx.x * blockDim.x + threadIdx.x;
  if (t >= total) return;
  int g = t / 10, c = t % 10;
  float acc = bc[c];
#pragma unroll
  for (int h = 0; h < 64; ++h) acc += pooled[g * 64 + h] * Wc[h * 10 + c];
  out[t] = acc;
}

extern "C" void kernel_launch(void* const* d_in, const int* in_sizes, int n_in,
                              void* d_out, int out_size, void* d_ws, size_t ws_size,
                              hipStream_t stream) {
  const float* x = (const float*)d_in[0];
  const void* ei = d_in[1];
  const void* batch = d_in[2];
  const float* W1 = (const float*)d_in[3];
  const float* b1 = (const float*)d_in[4];
  const float* W2 = (const float*)d_in[5];
  const float* b2 = (const float*)d_in[6];
  const float* W3 = (const float*)d_in[7];
  const float* b3 = (const float*)d_in[8];
  const float* Wc = (const float*)d_in[9];
  const float* bc = (const float*)d_in[10];
  float* out = (float*)d_out;

  const int N = in_sizes[0] / 128;
  const int E = in_sizes[1] / 2;
  const int G = out_size / 10;
  const int NB = (N + 2047) / 2048;

  char* W = (char*)d_ws;
  size_t off = 0;
  auto take = [&](size_t b) -> void* {
    void* p = W + off;
    off += (b + 255) & ~(size_t)255;
    return p;
  };
  int* flag = (int*)take(4);
  int* deg = (int*)take((size_t)4 * N);
  int* rowptr = (int*)take((size_t)4 * (N + 1));
  int* cursor = (int*)take((size_t)4 * N);
  int* bsum = (int*)take((size_t)4 * (NB + 1));
  float* dinv = (float*)take((size_t)4 * N);
  int* csr = (int*)take((size_t)4 * E);
  float* hs = (float*)take((size_t)4 * N * 64);
  float* cur = (float*)take((size_t)4 * N * 64);
  float* pooled = (float*)take((size_t)4 * G * 64);
  (void)ws_size;

  hipMemsetAsync(deg, 0, (size_t)4 * N, stream);
  hipMemsetAsync(cursor, 0, (size_t)4 * N, stream);

  k_detect<<<1, 256, 0, stream>>>((const unsigned*)ei, flag);
  k_deg<<<4096, 256, 0, stream>>>(ei, E, flag, deg);
  k_dinv<<<(N + 255) / 256, 256, 0, stream>>>(deg, dinv, N);
  k_scan_a<<<NB, 256, 0, stream>>>(deg, N, bsum);
  k_scan_b<<<1, 64, 0, stream>>>(bsum, NB);
  k_scan_c<<<NB, 256, 0, stream>>>(deg, N, bsum, rowptr, NB);
  k_scatter<<<4096, 256, 0, stream>>>(ei, E, flag, rowptr, cursor, csr);

  // layer 1: x[N,128] @ W1 -> hs; aggregate -> cur
  k_gemm_hs<128><<<2048, 256, 0, stream>>>(x, W1, dinv, hs, N);
  k_agg<<<2048, 256, 0, stream>>>(hs, rowptr, csr, dinv, b1, cur, N);
  // layer 2
  k_gemm_hs<64><<<2048, 256, 0, stream>>>(cur, W2, dinv, hs, N);
  k_agg<<<2048, 256, 0, stream>>>(hs, rowptr, csr, dinv, b2, cur, N);
  // layer 3
  k_gemm_hs<64><<<2048, 256, 0, stream>>>(cur, W3, dinv, hs, N);
  k_agg<<<2048, 256, 0, stream>>>(hs, rowptr, csr, dinv, b3, cur, N);

  k_pool<<<G, 256, 0, stream>>>(cur, batch, flag, pooled, N);
  k_classify<<<(G * 10 + 255) / 256, 256, 0, stream>>>(pooled, Wc, bc, out, G * 10);
}

// Round 2
// 1014.549 us; speedup vs baseline: 3.9409x; 3.9409x over previous
//
#include <hip/hip_runtime.h>

// ---------------------------------------------------------------------------
// MalwareGNN: 3-layer GCN (transform -> normalized aggregate) + mean pool + FC
//   * detect int32 vs int64 indices on device (flag in ws)
//   * build dst-CSR once per call (histogram -> scan -> scatter)
//   * per layer: GEMM with fused dinv scaling (hs = dinv * (x@W)) -- waves own
//     16 rows each, W in LDS, no shuffles, no LDS staging of X (each 16B of X
//     read exactly once via wave-uniform float4 loads)
//   * gather-aggregate: wave-per-node, lane = feature, 4x unrolled gathers
//   * self-loops analytic: out = relu(dinv*(hs[i]+sum hs[src])+b)
//   * mean-pool via per-graph binary search on sorted batch, then tiny FC
// ---------------------------------------------------------------------------

__global__ void k_detect(const unsigned* __restrict__ ei, int* __restrict__ flag) {
  __shared__ int any;
  if (threadIdx.x == 0) any = 0;
  __syncthreads();
  unsigned v = 0;
  for (int i = threadIdx.x; i < 8192; i += blockDim.x) v |= ei[2 * i + 1];
  if (v) atomicOr(&any, 1);
  __syncthreads();
  if (threadIdx.x == 0) *flag = (any == 0) ? 1 : 0;  // 1 => int64 indices
}

__device__ __forceinline__ int load_idx(const void* p, long long i, bool wide) {
  return wide ? (int)((const long long*)p)[i] : ((const int*)p)[i];
}

__global__ void k_deg(const void* __restrict__ ei, int E, const int* __restrict__ flag,
                      int* __restrict__ deg) {
  bool wide = (*flag != 0);
  for (int e = blockIdx.x * blockDim.x + threadIdx.x; e < E; e += gridDim.x * blockDim.x) {
    int d = load_idx(ei, (long long)E + e, wide);
    atomicAdd(&deg[d], 1);
  }
}

__global__ void k_dinv(const int* __restrict__ deg, float* __restrict__ dinv, int N) {
  int i = blockIdx.x * blockDim.x + threadIdx.x;
  if (i < N) dinv[i] = rsqrtf((float)(deg[i] + 1));  // +1 self loop
}

// ---- exclusive scan of deg[N] -> rowptr[N+1], 2048 items/block -------------
__global__ void k_scan_a(const int* __restrict__ deg, int N, int* __restrict__ bsum) {
  __shared__ int sh[256];
  int base = blockIdx.x * 2048;
  int s = 0;
  for (int i = threadIdx.x; i < 2048; i += 256) {
    int idx = base + i;
    s += (idx < N) ? deg[idx] : 0;
  }
  sh[threadIdx.x] = s;
  __syncthreads();
  for (int off = 128; off > 0; off >>= 1) {
    if (threadIdx.x < off) sh[threadIdx.x] += sh[threadIdx.x + off];
    __syncthreads();
  }
  if (threadIdx.x == 0) bsum[blockIdx.x] = sh[0];
}

__global__ void k_scan_b(int* __restrict__ bsum, int nb) {
  if (threadIdx.x == 0) {
    int run = 0;
    for (int i = 0; i < nb; ++i) { int v = bsum[i]; bsum[i] = run; run += v; }
    bsum[nb] = run;
  }
}

__global__ void k_scan_c(const int* __restrict__ deg, int N, const int* __restrict__ bsum,
                         int* __restrict__ rowptr, int nb) {
  __shared__ int sh[256];
  int base = blockIdx.x * 2048;
  int v[8];
  int s = 0;
#pragma unroll
  for (int j = 0; j < 8; ++j) {
    int idx = base + threadIdx.x * 8 + j;
    v[j] = (idx < N) ? deg[idx] : 0;
    s += v[j];
  }
  sh[threadIdx.x] = s;
  __syncthreads();
  for (int off = 1; off < 256; off <<= 1) {
    int t = (threadIdx.x >= off) ? sh[threadIdx.x - off] : 0;
    __syncthreads();
    sh[threadIdx.x] += t;
    __syncthreads();
  }
  int excl = (threadIdx.x ? sh[threadIdx.x - 1] : 0) + bsum[blockIdx.x];
#pragma unroll
  for (int j = 0; j < 8; ++j) {
    int idx = base + threadIdx.x * 8 + j;
    if (idx < N) rowptr[idx] = excl;
    excl += v[j];
  }
  if (blockIdx.x == gridDim.x - 1 && threadIdx.x == 255) rowptr[N] = bsum[nb];
}

__global__ void k_scatter(const void* __restrict__ ei, int E, const int* __restrict__ flag,
                          const int* __restrict__ rowptr, int* __restrict__ cursor,
                          int* __restrict__ csr) {
  bool wide = (*flag != 0);
  for (int e = blockIdx.x * blockDim.x + threadIdx.x; e < E; e += gridDim.x * blockDim.x) {
    int s = load_idx(ei, e, wide);
    int d = load_idx(ei, (long long)E + e, wide);
    int pos = rowptr[d] + atomicAdd(&cursor[d], 1);
    csr[pos] = s;
  }
}

// ---- hs = dinv * (X @ W): block = 4 waves, each wave owns 16 rows of a
// 64-row tile. W in LDS [K][64] (lane=col, conflict-free). X read straight
// from global as wave-uniform float4 (each 16B read exactly once). ----------
template <int K>
__global__ __launch_bounds__(256) void k_gemm_hs(const float* __restrict__ X,
                                                 const float* __restrict__ W,
                                                 const float* __restrict__ dinv,
                                                 float* __restrict__ HS, int N) {
  __shared__ float Wl[K * 64];
  for (int i = threadIdx.x; i < K * 64; i += 256) Wl[i] = W[i];
  __syncthreads();
  const int col = threadIdx.x & 63;
  const int rw = threadIdx.x >> 6;
  for (long long t = blockIdx.x; t * 64 < N; t += gridDim.x) {
    const long long r0 = t * 64;
    const int rows = (int)((N - r0) < 64 ? (N - r0) : 64);
    float acc[16];
#pragma unroll
    for (int r = 0; r < 16; ++r) acc[r] = 0.f;
    for (int k0 = 0; k0 < K; k0 += 4) {
      const float w0 = Wl[(k0 + 0) * 64 + col];
      const float w1 = Wl[(k0 + 1) * 64 + col];
      const float w2 = Wl[(k0 + 2) * 64 + col];
      const float w3 = Wl[(k0 + 3) * 64 + col];
#pragma unroll
      for (int r = 0; r < 16; ++r) {
        int lr = r * 4 + rw;
        if (lr >= rows) lr = rows - 1;  // wave-uniform clamp; result unused
        const float4 xv = *(const float4*)&X[(r0 + lr) * K + k0];
        acc[r] = fmaf(xv.w, w3, fmaf(xv.z, w2, fmaf(xv.y, w1, fmaf(xv.x, w0, acc[r]))));
      }
    }
#pragma unroll
    for (int r = 0; r < 16; ++r) {
      const int lr = r * 4 + rw;
      if (lr < rows) {
        const long long row = r0 + lr;
        HS[row * 64 + col] = dinv[row] * acc[r];
      }
    }
  }
}

// ---- out[i] = relu(dinv[i]*(hs[i] + sum_{src in(i)} hs[src]) + b) ----------
__global__ void k_agg(const float* __restrict__ HS, const int* __restrict__ rowptr,
                      const int* __restrict__ csr, const float* __restrict__ dinv,
                      const float* __restrict__ bias, float* __restrict__ OUT, int N) {
  const int lane = threadIdx.x & 63;
  const int wid = threadIdx.x >> 6;
  const int wavesPerBlock = blockDim.x >> 6;
  const float b = bias[lane];
  for (int node = blockIdx.x * wavesPerBlock + wid; node < N;
       node += wavesPerBlock * gridDim.x) {
    const int s0 = rowptr[node], s1 = rowptr[node + 1];
    float acc = HS[(long long)node * 64 + lane];  // self loop
    float acc2 = 0.f;
    for (int base = s0; base < s1; base += 64) {
      int m = s1 - base;
      if (m > 64) m = 64;
      const int idx = (base + lane < s1) ? csr[base + lane] : 0;
      int j = 0;
      for (; j + 4 <= m; j += 4) {
        const int a = __shfl(idx, j, 64);
        const int bb = __shfl(idx, j + 1, 64);
        const int c = __shfl(idx, j + 2, 64);
        const int d = __shfl(idx, j + 3, 64);
        const float v0 = HS[(long long)a * 64 + lane];
        const float v1 = HS[(long long)bb * 64 + lane];
        const float v2 = HS[(long long)c * 64 + lane];
        const float v3 = HS[(long long)d * 64 + lane];
        acc += v0 + v2;
        acc2 += v1 + v3;
      }
      for (; j < m; ++j) {
        const int s = __shfl(idx, j, 64);
        acc += HS[(long long)s * 64 + lane];
      }
    }
    OUT[(long long)node * 64 + lane] = fmaxf(fmaf(dinv[node], acc + acc2, b), 0.f);
  }
}

// ---- mean pool per graph (batch is sorted) ---------------------------------
__global__ void k_pool(const float* __restrict__ H, const void* __restrict__ batch,
                       const int* __restrict__ flag, float* __restrict__ pooled, int N) {
  __shared__ int se[2];
  __shared__ float red[4][64];
  bool wide = (*flag != 0);
  int g = blockIdx.x;
  if (threadIdx.x < 2) {
    int target = g + threadIdx.x;
    int lo = 0, hi = N;
    while (lo < hi) {
      int mid = (lo + hi) >> 1;
      long long v = wide ? ((const long long*)batch)[mid] : (long long)((const int*)batch)[mid];
      if (v < target) lo = mid + 1; else hi = mid;
    }
    se[threadIdx.x] = lo;
  }
  __syncthreads();
  int s = se[0], e = se[1];
  int lane = threadIdx.x & 63, wid = threadIdx.x >> 6;
  float acc = 0.f;
  for (int r = s + wid; r < e; r += 4) acc += H[(long long)r * 64 + lane];
  red[wid][lane] = acc;
  __syncthreads();
  if (wid == 0) {
    float v = red[0][lane] + red[1][lane] + red[2][lane] + red[3][lane];
    float cnt = (float)(e - s);
    pooled[g * 64 + lane] = v / fmaxf(cnt, 1.f);
  }
}

__global__ void k_classify(const float* __restrict__ pooled, const float* __restrict__ Wc,
                           const float* __restrict__ bc, float* __restrict__ out, int total) {
  int t = blockIdx.x * blockDim.x + threadIdx.x;
  if (t >= total) return;
  int g = t / 10, c = t % 10;
  float acc = bc[c];
#pragma unroll
  for (int h = 0; h < 64; ++h) acc += pooled[g * 64 + h] * Wc[h * 10 + c];
  out[t] = acc;
}

extern "C" void kernel_launch(void* const* d_in, const int* in_sizes, int n_in,
                              void* d_out, int out_size, void* d_ws, size_t ws_size,
                              hipStream_t stream) {
  const float* x = (const float*)d_in[0];
  const void* ei = d_in[1];
  const void* batch = d_in[2];
  const float* W1 = (const float*)d_in[3];
  const float* b1 = (const float*)d_in[4];
  const float* W2 = (const float*)d_in[5];
  const float* b2 = (const float*)d_in[6];
  const float* W3 = (const float*)d_in[7];
  const float* b3 = (const float*)d_in[8];
  const float* Wc = (const float*)d_in[9];
  const float* bc = (const float*)d_in[10];
  float* out = (float*)d_out;

  const int N = in_sizes[0] / 128;
  const int E = in_sizes[1] / 2;
  const int G = out_size / 10;
  const int NB = (N + 2047) / 2048;

  char* W = (char*)d_ws;
  size_t off = 0;
  auto take = [&](size_t b) -> void* {
    void* p = W + off;
    off += (b + 255) & ~(size_t)255;
    return p;
  };
  int* flag = (int*)take(4);
  int* deg = (int*)take((size_t)4 * N);
  int* rowptr = (int*)take((size_t)4 * (N + 1));
  int* cursor = (int*)take((size_t)4 * N);
  int* bsum = (int*)take((size_t)4 * (NB + 1));
  float* dinv = (float*)take((size_t)4 * N);
  int* csr = (int*)take((size_t)4 * E);
  float* hs = (float*)take((size_t)4 * N * 64);
  float* cur = (float*)take((size_t)4 * N * 64);
  float* pooled = (float*)take((size_t)4 * G * 64);
  (void)ws_size;

  hipMemsetAsync(deg, 0, (size_t)4 * N, stream);
  hipMemsetAsync(cursor, 0, (size_t)4 * N, stream);

  k_detect<<<1, 256, 0, stream>>>((const unsigned*)ei, flag);
  k_deg<<<4096, 256, 0, stream>>>(ei, E, flag, deg);
  k_dinv<<<(N + 255) / 256, 256, 0, stream>>>(deg, dinv, N);
  k_scan_a<<<NB, 256, 0, stream>>>(deg, N, bsum);
  k_scan_b<<<1, 64, 0, stream>>>(bsum, NB);
  k_scan_c<<<NB, 256, 0, stream>>>(deg, N, bsum, rowptr, NB);
  k_scatter<<<4096, 256, 0, stream>>>(ei, E, flag, rowptr, cursor, csr);

  const int TILES = (N + 63) / 64;
  // layer 1: x[N,128] @ W1 -> hs; aggregate -> cur
  k_gemm_hs<128><<<TILES, 256, 0, stream>>>(x, W1, dinv, hs, N);
  k_agg<<<4096, 256, 0, stream>>>(hs, rowptr, csr, dinv, b1, cur, N);
  // layer 2
  k_gemm_hs<64><<<TILES, 256, 0, stream>>>(cur, W2, dinv, hs, N);
  k_agg<<<4096, 256, 0, stream>>>(hs, rowptr, csr, dinv, b2, cur, N);
  // layer 3
  k_gemm_hs<64><<<TILES, 256, 0, stream>>>(cur, W3, dinv, hs, N);
  k_agg<<<4096, 256, 0, stream>>>(hs, rowptr, csr, dinv, b3, cur, N);

  k_pool<<<G, 256, 0, stream>>>(cur, batch, flag, pooled, N);
  k_classify<<<(G * 10 + 255) / 256, 256, 0, stream>>>(pooled, Wc, bc, out, G * 10);
}

// Round 3
// 941.287 us; speedup vs baseline: 4.2477x; 1.0778x over previous
//
#include <hip/hip_runtime.h>

// ---------------------------------------------------------------------------
// MalwareGNN: 3-layer GCN (transform -> normalized aggregate) + mean pool + FC
//   * detect int32 vs int64 indices on device (flag in ws)
//   * build dst-CSR once per call: range-partitioned histogram + scatter
//     (block = (dst-range, edge-chunk); bid%8 ~ XCD so each range's writes
//     and atomics stay in one XCD's L2 -> kills the 16x write amplification)
//   * per layer: GEMM with fused dinv scaling (hs = dinv * (x@W)); waves own
//     16 rows, W in LDS, wave-uniform float4 X loads (each 16B read once)
//   * gather-aggregate: wave-per-node, lane = feature, 4x unrolled gathers
//   * self-loops analytic: out = relu(dinv*(hs[i]+sum hs[src])+b)
//   * mean-pool via per-graph binary search on sorted batch, then tiny FC
// ---------------------------------------------------------------------------

#define RGRP 8  // dst ranges (~XCD count)

__global__ void k_detect(const unsigned* __restrict__ ei, int* __restrict__ flag) {
  __shared__ int any;
  if (threadIdx.x == 0) any = 0;
  __syncthreads();
  unsigned v = 0;
  for (int i = threadIdx.x; i < 8192; i += blockDim.x) v |= ei[2 * i + 1];
  if (v) atomicOr(&any, 1);
  __syncthreads();
  if (threadIdx.x == 0) *flag = (any == 0) ? 1 : 0;  // 1 => int64 indices
}

__device__ __forceinline__ int load_idx(const void* p, long long i, bool wide) {
  return wide ? (int)((const long long*)p)[i] : ((const int*)p)[i];
}

// deg histogram, range-partitioned: only this block's dst range -> atomics
// stay local to (likely) one XCD's L2.
__global__ void k_deg(const void* __restrict__ ei, int E, const int* __restrict__ flag,
                      int* __restrict__ deg, int N) {
  const bool wide = (*flag != 0);
  const int range = blockIdx.x & (RGRP - 1);
  const int cblk = blockIdx.x >> 3;
  const int nchunk = gridDim.x >> 3;
  const int lo = (int)((long long)N * range / RGRP);
  const int hi = (int)((long long)N * (range + 1) / RGRP);
  for (int e = cblk * blockDim.x + threadIdx.x; e < E; e += nchunk * blockDim.x) {
    const int d = load_idx(ei, (long long)E + e, wide);
    if (d >= lo && d < hi) atomicAdd(&deg[d], 1);
  }
}

__global__ void k_dinv(const int* __restrict__ deg, float* __restrict__ dinv, int N) {
  int i = blockIdx.x * blockDim.x + threadIdx.x;
  if (i < N) dinv[i] = rsqrtf((float)(deg[i] + 1));  // +1 self loop
}

// ---- exclusive scan of deg[N] -> rowptr[N+1], 2048 items/block -------------
__global__ void k_scan_a(const int* __restrict__ deg, int N, int* __restrict__ bsum) {
  __shared__ int sh[256];
  int base = blockIdx.x * 2048;
  int s = 0;
  for (int i = threadIdx.x; i < 2048; i += 256) {
    int idx = base + i;
    s += (idx < N) ? deg[idx] : 0;
  }
  sh[threadIdx.x] = s;
  __syncthreads();
  for (int off = 128; off > 0; off >>= 1) {
    if (threadIdx.x < off) sh[threadIdx.x] += sh[threadIdx.x + off];
    __syncthreads();
  }
  if (threadIdx.x == 0) bsum[blockIdx.x] = sh[0];
}

__global__ void k_scan_b(int* __restrict__ bsum, int nb) {
  if (threadIdx.x == 0) {
    int run = 0;
    for (int i = 0; i < nb; ++i) { int v = bsum[i]; bsum[i] = run; run += v; }
    bsum[nb] = run;
  }
}

// rowptr written; cursor initialized to rowptr in the same pass.
__global__ void k_scan_c(const int* __restrict__ deg, int N, const int* __restrict__ bsum,
                         int* __restrict__ rowptr, int* __restrict__ cursor, int nb) {
  __shared__ int sh[256];
  int base = blockIdx.x * 2048;
  int v[8];
  int s = 0;
#pragma unroll
  for (int j = 0; j < 8; ++j) {
    int idx = base + threadIdx.x * 8 + j;
    v[j] = (idx < N) ? deg[idx] : 0;
    s += v[j];
  }
  sh[threadIdx.x] = s;
  __syncthreads();
  for (int off = 1; off < 256; off <<= 1) {
    int t = (threadIdx.x >= off) ? sh[threadIdx.x - off] : 0;
    __syncthreads();
    sh[threadIdx.x] += t;
    __syncthreads();
  }
  int excl = (threadIdx.x ? sh[threadIdx.x - 1] : 0) + bsum[blockIdx.x];
#pragma unroll
  for (int j = 0; j < 8; ++j) {
    int idx = base + threadIdx.x * 8 + j;
    if (idx < N) { rowptr[idx] = excl; cursor[idx] = excl; }
    excl += v[j];
  }
  if (blockIdx.x == gridDim.x - 1 && threadIdx.x == 255) rowptr[N] = bsum[nb];
}

// range-partitioned scatter: csr writes + cursor atomics confined to one
// dst-range region per block group -> L2-local, full-line writebacks.
__global__ void k_scatter(const void* __restrict__ ei, int E, const int* __restrict__ flag,
                          int* __restrict__ cursor, int* __restrict__ csr, int N) {
  const bool wide = (*flag != 0);
  const int range = blockIdx.x & (RGRP - 1);
  const int cblk = blockIdx.x >> 3;
  const int nchunk = gridDim.x >> 3;
  const int lo = (int)((long long)N * range / RGRP);
  const int hi = (int)((long long)N * (range + 1) / RGRP);
  for (int e = cblk * blockDim.x + threadIdx.x; e < E; e += nchunk * blockDim.x) {
    const int d = load_idx(ei, (long long)E + e, wide);
    if (d >= lo && d < hi) {
      const int s = load_idx(ei, e, wide);
      const int pos = atomicAdd(&cursor[d], 1);
      csr[pos] = s;
    }
  }
}

// ---- hs = dinv * (X @ W): block = 4 waves, each wave owns 16 rows of a
// 64-row tile. W in LDS [K][64] (lane=col, conflict-free). ------------------
template <int K>
__global__ __launch_bounds__(256) void k_gemm_hs(const float* __restrict__ X,
                                                 const float* __restrict__ W,
                                                 const float* __restrict__ dinv,
                                                 float* __restrict__ HS, int N) {
  __shared__ float Wl[K * 64];
  for (int i = threadIdx.x; i < K * 64; i += 256) Wl[i] = W[i];
  __syncthreads();
  const int col = threadIdx.x & 63;
  const int rw = threadIdx.x >> 6;
  for (long long t = blockIdx.x; t * 64 < N; t += gridDim.x) {
    const long long r0 = t * 64;
    const int rows = (int)((N - r0) < 64 ? (N - r0) : 64);
    float acc[16];
#pragma unroll
    for (int r = 0; r < 16; ++r) acc[r] = 0.f;
    for (int k0 = 0; k0 < K; k0 += 4) {
      const float w0 = Wl[(k0 + 0) * 64 + col];
      const float w1 = Wl[(k0 + 1) * 64 + col];
      const float w2 = Wl[(k0 + 2) * 64 + col];
      const float w3 = Wl[(k0 + 3) * 64 + col];
#pragma unroll
      for (int r = 0; r < 16; ++r) {
        int lr = r * 4 + rw;
        if (lr >= rows) lr = rows - 1;  // wave-uniform clamp; result unused
        const float4 xv = *(const float4*)&X[(r0 + lr) * K + k0];
        acc[r] = fmaf(xv.w, w3, fmaf(xv.z, w2, fmaf(xv.y, w1, fmaf(xv.x, w0, acc[r]))));
      }
    }
#pragma unroll
    for (int r = 0; r < 16; ++r) {
      const int lr = r * 4 + rw;
      if (lr < rows) {
        const long long row = r0 + lr;
        HS[row * 64 + col] = dinv[row] * acc[r];
      }
    }
  }
}

// ---- out[i] = relu(dinv[i]*(hs[i] + sum_{src in(i)} hs[src]) + b) ----------
__global__ void k_agg(const float* __restrict__ HS, const int* __restrict__ rowptr,
                      const int* __restrict__ csr, const float* __restrict__ dinv,
                      const float* __restrict__ bias, float* __restrict__ OUT, int N) {
  const int lane = threadIdx.x & 63;
  const int wid = threadIdx.x >> 6;
  const int wavesPerBlock = blockDim.x >> 6;
  const float b = bias[lane];
  for (int node = blockIdx.x * wavesPerBlock + wid; node < N;
       node += wavesPerBlock * gridDim.x) {
    const int s0 = rowptr[node], s1 = rowptr[node + 1];
    float acc = HS[(long long)node * 64 + lane];  // self loop
    float acc2 = 0.f;
    for (int base = s0; base < s1; base += 64) {
      int m = s1 - base;
      if (m > 64) m = 64;
      const int idx = (base + lane < s1) ? csr[base + lane] : 0;
      int j = 0;
      for (; j + 4 <= m; j += 4) {
        const int a = __shfl(idx, j, 64);
        const int bb = __shfl(idx, j + 1, 64);
        const int c = __shfl(idx, j + 2, 64);
        const int d = __shfl(idx, j + 3, 64);
        const float v0 = HS[(long long)a * 64 + lane];
        const float v1 = HS[(long long)bb * 64 + lane];
        const float v2 = HS[(long long)c * 64 + lane];
        const float v3 = HS[(long long)d * 64 + lane];
        acc += v0 + v2;
        acc2 += v1 + v3;
      }
      for (; j < m; ++j) {
        const int s = __shfl(idx, j, 64);
        acc += HS[(long long)s * 64 + lane];
      }
    }
    OUT[(long long)node * 64 + lane] = fmaxf(fmaf(dinv[node], acc + acc2, b), 0.f);
  }
}

// ---- mean pool per graph (batch is sorted) ---------------------------------
__global__ void k_pool(const float* __restrict__ H, const void* __restrict__ batch,
                       const int* __restrict__ flag, float* __restrict__ pooled, int N) {
  __shared__ int se[2];
  __shared__ float red[4][64];
  bool wide = (*flag != 0);
  int g = blockIdx.x;
  if (threadIdx.x < 2) {
    int target = g + threadIdx.x;
    int lo = 0, hi = N;
    while (lo < hi) {
      int mid = (lo + hi) >> 1;
      long long v = wide ? ((const long long*)batch)[mid] : (long long)((const int*)batch)[mid];
      if (v < target) lo = mid + 1; else hi = mid;
    }
    se[threadIdx.x] = lo;
  }
  __syncthreads();
  int s = se[0], e = se[1];
  int lane = threadIdx.x & 63, wid = threadIdx.x >> 6;
  float acc = 0.f;
  for (int r = s + wid; r < e; r += 4) acc += H[(long long)r * 64 + lane];
  red[wid][lane] = acc;
  __syncthreads();
  if (wid == 0) {
    float v = red[0][lane] + red[1][lane] + red[2][lane] + red[3][lane];
    float cnt = (float)(e - s);
    pooled[g * 64 + lane] = v / fmaxf(cnt, 1.f);
  }
}

__global__ void k_classify(const float* __restrict__ pooled, const float* __restrict__ Wc,
                           const float* __restrict__ bc, float* __restrict__ out, int total) {
  int t = blockIdx.x * blockDim.x + threadIdx.x;
  if (t >= total) return;
  int g = t / 10, c = t % 10;
  float acc = bc[c];
#pragma unroll
  for (int h = 0; h < 64; ++h) acc += pooled[g * 64 + h] * Wc[h * 10 + c];
  out[t] = acc;
}

extern "C" void kernel_launch(void* const* d_in, const int* in_sizes, int n_in,
                              void* d_out, int out_size, void* d_ws, size_t ws_size,
                              hipStream_t stream) {
  const float* x = (const float*)d_in[0];
  const void* ei = d_in[1];
  const void* batch = d_in[2];
  const float* W1 = (const float*)d_in[3];
  const float* b1 = (const float*)d_in[4];
  const float* W2 = (const float*)d_in[5];
  const float* b2 = (const float*)d_in[6];
  const float* W3 = (const float*)d_in[7];
  const float* b3 = (const float*)d_in[8];
  const float* Wc = (const float*)d_in[9];
  const float* bc = (const float*)d_in[10];
  float* out = (float*)d_out;

  const int N = in_sizes[0] / 128;
  const int E = in_sizes[1] / 2;
  const int G = out_size / 10;
  const int NB = (N + 2047) / 2048;

  char* W = (char*)d_ws;
  size_t off = 0;
  auto take = [&](size_t b) -> void* {
    void* p = W + off;
    off += (b + 255) & ~(size_t)255;
    return p;
  };
  int* flag = (int*)take(4);
  int* deg = (int*)take((size_t)4 * N);
  int* rowptr = (int*)take((size_t)4 * (N + 1));
  int* cursor = (int*)take((size_t)4 * N);
  int* bsum = (int*)take((size_t)4 * (NB + 1));
  float* dinv = (float*)take((size_t)4 * N);
  int* csr = (int*)take((size_t)4 * E);
  float* hs = (float*)take((size_t)4 * N * 64);
  float* cur = (float*)take((size_t)4 * N * 64);
  float* pooled = (float*)take((size_t)4 * G * 64);
  (void)ws_size;

  hipMemsetAsync(deg, 0, (size_t)4 * N, stream);

  k_detect<<<1, 256, 0, stream>>>((const unsigned*)ei, flag);
  k_deg<<<4096, 256, 0, stream>>>(ei, E, flag, deg, N);
  k_dinv<<<(N + 255) / 256, 256, 0, stream>>>(deg, dinv, N);
  k_scan_a<<<NB, 256, 0, stream>>>(deg, N, bsum);
  k_scan_b<<<1, 64, 0, stream>>>(bsum, NB);
  k_scan_c<<<NB, 256, 0, stream>>>(deg, N, bsum, rowptr, cursor, NB);
  k_scatter<<<4096, 256, 0, stream>>>(ei, E, flag, cursor, csr, N);

  const int TILES = (N + 63) / 64;
  // layer 1: x[N,128] @ W1 -> hs; aggregate -> cur
  k_gemm_hs<128><<<TILES, 256, 0, stream>>>(x, W1, dinv, hs, N);
  k_agg<<<4096, 256, 0, stream>>>(hs, rowptr, csr, dinv, b1, cur, N);
  // layer 2
  k_gemm_hs<64><<<TILES, 256, 0, stream>>>(cur, W2, dinv, hs, N);
  k_agg<<<4096, 256, 0, stream>>>(hs, rowptr, csr, dinv, b2, cur, N);
  // layer 3
  k_gemm_hs<64><<<TILES, 256, 0, stream>>>(cur, W3, dinv, hs, N);
  k_agg<<<4096, 256, 0, stream>>>(hs, rowptr, csr, dinv, b3, cur, N);

  k_pool<<<G, 256, 0, stream>>>(cur, batch, flag, pooled, N);
  k_classify<<<(G * 10 + 255) / 256, 256, 0, stream>>>(pooled, Wc, bc, out, G * 10);
}

// Round 4
// 819.835 us; speedup vs baseline: 4.8769x; 1.1481x over previous
//
#include <hip/hip_runtime.h>

// ---------------------------------------------------------------------------
// MalwareGNN: 3-layer GCN (transform -> normalized aggregate) + mean pool + FC
//   * detect int32 vs int64 indices on device (flag in ws)
//   * build dst-CSR once per call: range-partitioned histogram + scatter
//     (keeps csr writes/atomics L2-local per dst range -> no write amp)
//   * per layer: GEMM hs = dinv*(X@W). 64-row tile/block, 4 waves, lane=col.
//     X staged in LDS k-chunks via coalesced float4; compute reads X as
//     wave-uniform ds_read_b128 broadcast (conflict-free), W from LDS (2-way
//     = free). No clamps or address mul in the hot loop.
//   * gather-aggregate: wave-per-node, lane = feature, 8x unrolled gathers
//   * self-loops analytic: out = relu(dinv*(hs[i]+sum hs[src])+b)
//   * mean-pool via per-graph binary search on sorted batch, then tiny FC
// ---------------------------------------------------------------------------

#define RGRP 8  // dst ranges (~XCD count)

__global__ void k_detect(const unsigned* __restrict__ ei, int* __restrict__ flag) {
  __shared__ int any;
  if (threadIdx.x == 0) any = 0;
  __syncthreads();
  unsigned v = 0;
  for (int i = threadIdx.x; i < 8192; i += blockDim.x) v |= ei[2 * i + 1];
  if (v) atomicOr(&any, 1);
  __syncthreads();
  if (threadIdx.x == 0) *flag = (any == 0) ? 1 : 0;  // 1 => int64 indices
}

__device__ __forceinline__ int load_idx(const void* p, long long i, bool wide) {
  return wide ? (int)((const long long*)p)[i] : ((const int*)p)[i];
}

__global__ void k_deg(const void* __restrict__ ei, int E, const int* __restrict__ flag,
                      int* __restrict__ deg, int N) {
  const bool wide = (*flag != 0);
  const int range = blockIdx.x & (RGRP - 1);
  const int cblk = blockIdx.x >> 3;
  const int nchunk = gridDim.x >> 3;
  const int lo = (int)((long long)N * range / RGRP);
  const int hi = (int)((long long)N * (range + 1) / RGRP);
  for (int e = cblk * blockDim.x + threadIdx.x; e < E; e += nchunk * blockDim.x) {
    const int d = load_idx(ei, (long long)E + e, wide);
    if (d >= lo && d < hi) atomicAdd(&deg[d], 1);
  }
}

__global__ void k_dinv(const int* __restrict__ deg, float* __restrict__ dinv, int N) {
  int i = blockIdx.x * blockDim.x + threadIdx.x;
  if (i < N) dinv[i] = rsqrtf((float)(deg[i] + 1));  // +1 self loop
}

// ---- exclusive scan of deg[N] -> rowptr[N+1], 2048 items/block -------------
__global__ void k_scan_a(const int* __restrict__ deg, int N, int* __restrict__ bsum) {
  __shared__ int sh[256];
  int base = blockIdx.x * 2048;
  int s = 0;
  for (int i = threadIdx.x; i < 2048; i += 256) {
    int idx = base + i;
    s += (idx < N) ? deg[idx] : 0;
  }
  sh[threadIdx.x] = s;
  __syncthreads();
  for (int off = 128; off > 0; off >>= 1) {
    if (threadIdx.x < off) sh[threadIdx.x] += sh[threadIdx.x + off];
    __syncthreads();
  }
  if (threadIdx.x == 0) bsum[blockIdx.x] = sh[0];
}

__global__ void k_scan_b(int* __restrict__ bsum, int nb) {
  if (threadIdx.x == 0) {
    int run = 0;
    for (int i = 0; i < nb; ++i) { int v = bsum[i]; bsum[i] = run; run += v; }
    bsum[nb] = run;
  }
}

__global__ void k_scan_c(const int* __restrict__ deg, int N, const int* __restrict__ bsum,
                         int* __restrict__ rowptr, int* __restrict__ cursor, int nb) {
  __shared__ int sh[256];
  int base = blockIdx.x * 2048;
  int v[8];
  int s = 0;
#pragma unroll
  for (int j = 0; j < 8; ++j) {
    int idx = base + threadIdx.x * 8 + j;
    v[j] = (idx < N) ? deg[idx] : 0;
    s += v[j];
  }
  sh[threadIdx.x] = s;
  __syncthreads();
  for (int off = 1; off < 256; off <<= 1) {
    int t = (threadIdx.x >= off) ? sh[threadIdx.x - off] : 0;
    __syncthreads();
    sh[threadIdx.x] += t;
    __syncthreads();
  }
  int excl = (threadIdx.x ? sh[threadIdx.x - 1] : 0) + bsum[blockIdx.x];
#pragma unroll
  for (int j = 0; j < 8; ++j) {
    int idx = base + threadIdx.x * 8 + j;
    if (idx < N) { rowptr[idx] = excl; cursor[idx] = excl; }
    excl += v[j];
  }
  if (blockIdx.x == gridDim.x - 1 && threadIdx.x == 255) rowptr[N] = bsum[nb];
}

__global__ void k_scatter(const void* __restrict__ ei, int E, const int* __restrict__ flag,
                          int* __restrict__ cursor, int* __restrict__ csr, int N) {
  const bool wide = (*flag != 0);
  const int range = blockIdx.x & (RGRP - 1);
  const int cblk = blockIdx.x >> 3;
  const int nchunk = gridDim.x >> 3;
  const int lo = (int)((long long)N * range / RGRP);
  const int hi = (int)((long long)N * (range + 1) / RGRP);
  for (int e = cblk * blockDim.x + threadIdx.x; e < E; e += nchunk * blockDim.x) {
    const int d = load_idx(ei, (long long)E + e, wide);
    if (d >= lo && d < hi) {
      const int s = load_idx(ei, e, wide);
      const int pos = atomicAdd(&cursor[d], 1);
      csr[pos] = s;
    }
  }
}

// ---- hs = dinv * (X @ W) ---------------------------------------------------
// block = 4 waves, tile = 64 rows x 64 cols. lane = col. Wave rw owns rows
// r*4+rw (16 accs). X staged per 32-k chunk in LDS (coalesced float4 in,
// wave-uniform b128 broadcast out). W in LDS [K][64].
template <int K>
__global__ __launch_bounds__(256) void k_gemm_hs(const float* __restrict__ X,
                                                 const float* __restrict__ W,
                                                 const float* __restrict__ dinv,
                                                 float* __restrict__ HS, int N) {
  __shared__ float Wl[K * 64];
  __shared__ float Xl[64 * 32];
  for (int i = threadIdx.x; i < K * 64; i += 256) Wl[i] = W[i];
  const int col = threadIdx.x & 63;
  const int rw = threadIdx.x >> 6;
  const int srow = threadIdx.x >> 3;        // 0..31 staging row
  const int scol = (threadIdx.x & 7) * 4;   // 0,4,...,28 staging col

  const long long r0 = (long long)blockIdx.x * 64;
  const int rows = (int)((N - r0) < 64 ? (N - r0) : 64);

  float acc[16];
#pragma unroll
  for (int r = 0; r < 16; ++r) acc[r] = 0.f;

  for (int k0 = 0; k0 < K; k0 += 32) {
    __syncthreads();
#pragma unroll
    for (int p = 0; p < 2; ++p) {
      const int row = srow + p * 32;
      const int src = (row < rows) ? row : 0;  // safe tail source
      const float4 v = *(const float4*)&X[(r0 + src) * K + k0 + scol];
      *(float4*)&Xl[row * 32 + scol] = v;
    }
    __syncthreads();
#pragma unroll
    for (int kk = 0; kk < 32; kk += 4) {
      const float w0 = Wl[(k0 + kk + 0) * 64 + col];
      const float w1 = Wl[(k0 + kk + 1) * 64 + col];
      const float w2 = Wl[(k0 + kk + 2) * 64 + col];
      const float w3 = Wl[(k0 + kk + 3) * 64 + col];
#pragma unroll
      for (int r = 0; r < 16; ++r) {
        const float4 xv = *(const float4*)&Xl[(r * 4 + rw) * 32 + kk];
        acc[r] = fmaf(xv.w, w3, fmaf(xv.z, w2, fmaf(xv.y, w1, fmaf(xv.x, w0, acc[r]))));
      }
    }
  }
#pragma unroll
  for (int r = 0; r < 16; ++r) {
    const int lr = r * 4 + rw;
    if (lr < rows) {
      const long long row = r0 + lr;
      HS[row * 64 + col] = dinv[row] * acc[r];
    }
  }
}

// ---- out[i] = relu(dinv[i]*(hs[i] + sum_{src in(i)} hs[src]) + b) ----------
__global__ void k_agg(const float* __restrict__ HS, const int* __restrict__ rowptr,
                      const int* __restrict__ csr, const float* __restrict__ dinv,
                      const float* __restrict__ bias, float* __restrict__ OUT, int N) {
  const int lane = threadIdx.x & 63;
  const int wid = threadIdx.x >> 6;
  const int wavesPerBlock = blockDim.x >> 6;
  const float b = bias[lane];
  for (int node = blockIdx.x * wavesPerBlock + wid; node < N;
       node += wavesPerBlock * gridDim.x) {
    const int s0 = rowptr[node], s1 = rowptr[node + 1];
    float a0 = HS[(long long)node * 64 + lane];  // self loop
    float a1 = 0.f, a2 = 0.f, a3 = 0.f;
    for (int base = s0; base < s1; base += 64) {
      int m = s1 - base;
      if (m > 64) m = 64;
      const int idx = (base + lane < s1) ? csr[base + lane] : 0;
      int j = 0;
      for (; j + 8 <= m; j += 8) {
        const int i0 = __shfl(idx, j + 0, 64);
        const int i1 = __shfl(idx, j + 1, 64);
        const int i2 = __shfl(idx, j + 2, 64);
        const int i3 = __shfl(idx, j + 3, 64);
        const int i4 = __shfl(idx, j + 4, 64);
        const int i5 = __shfl(idx, j + 5, 64);
        const int i6 = __shfl(idx, j + 6, 64);
        const int i7 = __shfl(idx, j + 7, 64);
        const float v0 = HS[(long long)i0 * 64 + lane];
        const float v1 = HS[(long long)i1 * 64 + lane];
        const float v2 = HS[(long long)i2 * 64 + lane];
        const float v3 = HS[(long long)i3 * 64 + lane];
        const float v4 = HS[(long long)i4 * 64 + lane];
        const float v5 = HS[(long long)i5 * 64 + lane];
        const float v6 = HS[(long long)i6 * 64 + lane];
        const float v7 = HS[(long long)i7 * 64 + lane];
        a0 += v0 + v4;
        a1 += v1 + v5;
        a2 += v2 + v6;
        a3 += v3 + v7;
      }
      for (; j < m; ++j) {
        const int s = __shfl(idx, j, 64);
        a0 += HS[(long long)s * 64 + lane];
      }
    }
    OUT[(long long)node * 64 + lane] =
        fmaxf(fmaf(dinv[node], (a0 + a1) + (a2 + a3), b), 0.f);
  }
}

// ---- mean pool per graph (batch is sorted) ---------------------------------
__global__ void k_pool(const float* __restrict__ H, const void* __restrict__ batch,
                       const int* __restrict__ flag, float* __restrict__ pooled, int N) {
  __shared__ int se[2];
  __shared__ float red[4][64];
  bool wide = (*flag != 0);
  int g = blockIdx.x;
  if (threadIdx.x < 2) {
    int target = g + threadIdx.x;
    int lo = 0, hi = N;
    while (lo < hi) {
      int mid = (lo + hi) >> 1;
      long long v = wide ? ((const long long*)batch)[mid] : (long long)((const int*)batch)[mid];
      if (v < target) lo = mid + 1; else hi = mid;
    }
    se[threadIdx.x] = lo;
  }
  __syncthreads();
  int s = se[0], e = se[1];
  int lane = threadIdx.x & 63, wid = threadIdx.x >> 6;
  float acc = 0.f;
  for (int r = s + wid; r < e; r += 4) acc += H[(long long)r * 64 + lane];
  red[wid][lane] = acc;
  __syncthreads();
  if (wid == 0) {
    float v = red[0][lane] + red[1][lane] + red[2][lane] + red[3][lane];
    float cnt = (float)(e - s);
    pooled[g * 64 + lane] = v / fmaxf(cnt, 1.f);
  }
}

__global__ void k_classify(const float* __restrict__ pooled, const float* __restrict__ Wc,
                           const float* __restrict__ bc, float* __restrict__ out, int total) {
  int t = blockIdx.x * blockDim.x + threadIdx.x;
  if (t >= total) return;
  int g = t / 10, c = t % 10;
  float acc = bc[c];
#pragma unroll
  for (int h = 0; h < 64; ++h) acc += pooled[g * 64 + h] * Wc[h * 10 + c];
  out[t] = acc;
}

extern "C" void kernel_launch(void* const* d_in, const int* in_sizes, int n_in,
                              void* d_out, int out_size, void* d_ws, size_t ws_size,
                              hipStream_t stream) {
  const float* x = (const float*)d_in[0];
  const void* ei = d_in[1];
  const void* batch = d_in[2];
  const float* W1 = (const float*)d_in[3];
  const float* b1 = (const float*)d_in[4];
  const float* W2 = (const float*)d_in[5];
  const float* b2 = (const float*)d_in[6];
  const float* W3 = (const float*)d_in[7];
  const float* b3 = (const float*)d_in[8];
  const float* Wc = (const float*)d_in[9];
  const float* bc = (const float*)d_in[10];
  float* out = (float*)d_out;

  const int N = in_sizes[0] / 128;
  const int E = in_sizes[1] / 2;
  const int G = out_size / 10;
  const int NB = (N + 2047) / 2048;

  char* W = (char*)d_ws;
  size_t off = 0;
  auto take = [&](size_t b) -> void* {
    void* p = W + off;
    off += (b + 255) & ~(size_t)255;
    return p;
  };
  int* flag = (int*)take(4);
  int* deg = (int*)take((size_t)4 * N);
  int* rowptr = (int*)take((size_t)4 * (N + 1));
  int* cursor = (int*)take((size_t)4 * N);
  int* bsum = (int*)take((size_t)4 * (NB + 1));
  float* dinv = (float*)take((size_t)4 * N);
  int* csr = (int*)take((size_t)4 * E);
  float* hs = (float*)take((size_t)4 * N * 64);
  float* cur = (float*)take((size_t)4 * N * 64);
  float* pooled = (float*)take((size_t)4 * G * 64);
  (void)ws_size;

  hipMemsetAsync(deg, 0, (size_t)4 * N, stream);

  k_detect<<<1, 256, 0, stream>>>((const unsigned*)ei, flag);
  k_deg<<<4096, 256, 0, stream>>>(ei, E, flag, deg, N);
  k_dinv<<<(N + 255) / 256, 256, 0, stream>>>(deg, dinv, N);
  k_scan_a<<<NB, 256, 0, stream>>>(deg, N, bsum);
  k_scan_b<<<1, 64, 0, stream>>>(bsum, NB);
  k_scan_c<<<NB, 256, 0, stream>>>(deg, N, bsum, rowptr, cursor, NB);
  k_scatter<<<4096, 256, 0, stream>>>(ei, E, flag, cursor, csr, N);

  const int TILES = (N + 63) / 64;
  // layer 1: x[N,128] @ W1 -> hs; aggregate -> cur
  k_gemm_hs<128><<<TILES, 256, 0, stream>>>(x, W1, dinv, hs, N);
  k_agg<<<4096, 256, 0, stream>>>(hs, rowptr, csr, dinv, b1, cur, N);
  // layer 2
  k_gemm_hs<64><<<TILES, 256, 0, stream>>>(cur, W2, dinv, hs, N);
  k_agg<<<4096, 256, 0, stream>>>(hs, rowptr, csr, dinv, b2, cur, N);
  // layer 3
  k_gemm_hs<64><<<TILES, 256, 0, stream>>>(cur, W3, dinv, hs, N);
  k_agg<<<4096, 256, 0, stream>>>(hs, rowptr, csr, dinv, b3, cur, N);

  k_pool<<<G, 256, 0, stream>>>(cur, batch, flag, pooled, N);
  k_classify<<<(G * 10 + 255) / 256, 256, 0, stream>>>(pooled, Wc, bc, out, G * 10);
}